// Round 12
// baseline (252.816 us; speedup 1.0000x reference)
//
#include <hip/hip_runtime.h>
#include <hip/hip_fp16.h>

#define NPIX 16384
#define CCH 256
#define INTR 128
#define REDD 32
#define NB 8
#define SLOPE 0.1f
#define BNEPS 1e-5f

typedef _Float16 f16x8 __attribute__((ext_vector_type(8)));
typedef __attribute__((ext_vector_type(16))) float f32x16;

// workspace offsets (floats)
#define OFF_GX    0            // 8*256*256 = 524288
#define OFF_YM    524288       // 2048 raw row sums (written by cvtrow)
#define OFF_SC    526336       // 2048
#define OFF_QS    530432       // 1024
#define OFF_VS    531456       // 1024
#define OFF_SWG   532480       // 128
#define OFF_TWG   532608       // 128
#define OFF_SOUT  532736       // 256
#define OFF_TOUT  532992       // 256
#define OFF_M     795392       // 8*128*128 = 131072
#define OFF_W7    1450752      // ushort f16 [8*256*256] = 1 MB
#define OFF_B6    1975040      // 2048 -> ends 1977088
#define OFF_XH    1977088      // ushort f16 x [8*256*16384] = 64 MB
#define OFF_PART  18754304     // f16 partials: NB*3*nch*16384 shorts (nch=64 -> ends 31337216 = 125 MB)

__device__ __forceinline__ unsigned short h1(float f) {
    __half h = __float2half(f);
    return __half_as_ushort(h);
}

__device__ __forceinline__ uint4 cvt8h(const float4 a, const float4 c) {
    __half2 p0 = __floats2half2_rn(a.x, a.y);
    __half2 p1 = __floats2half2_rn(a.z, a.w);
    __half2 p2 = __floats2half2_rn(c.x, c.y);
    __half2 p3 = __floats2half2_rn(c.z, c.w);
    uint4 r;
    r.x = *(unsigned int*)&p0; r.y = *(unsigned int*)&p1;
    r.z = *(unsigned int*)&p2; r.w = *(unsigned int*)&p3;
    return r;
}

__device__ __forceinline__ f16x8 cvt8hf(const float4 a, const float4 c) {
    uint4 u = cvt8h(a, c);
    return *(f16x8*)&u;
}

__device__ __forceinline__ void gload_lds16(const void* g, void* l) {
    __builtin_amdgcn_global_load_lds((const __attribute__((address_space(1))) void*)g,
                                     (__attribute__((address_space(3))) void*)l, 16, 0, 0);
}

// ---------- 1. x f32 -> xh f16 (once) + fused row sums ----------
__global__ __launch_bounds__(256) void cvtrow_kernel(const float* __restrict__ x,
                                                     unsigned short* __restrict__ xh,
                                                     float* __restrict__ ymsum) {
    int row = blockIdx.x;  // b*256 + c
    const float4* p4 = (const float4*)(x + (size_t)row * NPIX);
    uint4* o4 = (uint4*)(xh + (size_t)row * NPIX);
    float s = 0.f;
    for (int i = threadIdx.x; i < NPIX / 8; i += 256) {
        float4 v0 = p4[2 * i];
        float4 v1 = p4[2 * i + 1];
        s += (v0.x + v0.y) + (v0.z + v0.w) + (v1.x + v1.y) + (v1.z + v1.w);
        o4[i] = cvt8h(v0, v1);
    }
    for (int off = 32; off > 0; off >>= 1) s += __shfl_xor(s, off);
    __shared__ float red[4];
    if ((threadIdx.x & 63) == 0) red[threadIdx.x >> 6] = s;
    __syncthreads();
    if (threadIdx.x == 0)
        ymsum[row] = red[0] + red[1] + red[2] + red[3];
}

// ---------- 2. head: SE + BN-prep + qs/vs, fused ----------
__global__ __launch_bounds__(256) void head_kernel(const float* __restrict__ ymsum,
                                                   const float* __restrict__ se_w1,
                                                   const float* __restrict__ se_w2,
                                                   const float* __restrict__ wq,
                                                   const float* __restrict__ wv,
                                                   const float* __restrict__ g_wg, const float* __restrict__ be_wg,
                                                   const float* __restrict__ rm_wg, const float* __restrict__ rv_wg,
                                                   const float* __restrict__ g_out, const float* __restrict__ be_out,
                                                   const float* __restrict__ rm_out, const float* __restrict__ rv_out,
                                                   float* __restrict__ scale,
                                                   float* __restrict__ qs, float* __restrict__ vs,
                                                   float* __restrict__ swg, float* __restrict__ twg,
                                                   float* __restrict__ sout, float* __restrict__ tout) {
    int b = blockIdx.x, t = threadIdx.x;
    __shared__ float ys[CCH], y1s[REDD], rs[CCH];
    float ymr = ymsum[b * CCH + t];
    ys[t] = ymr * (1.f / 16384.f);
    if (b == 0) {
        if (t < INTR) {
            float s = g_wg[t] / sqrtf(rv_wg[t] + BNEPS);
            swg[t] = s;
            twg[t] = be_wg[t] - rm_wg[t] * s;
        }
        float s = g_out[t] / sqrtf(rv_out[t] + BNEPS);
        sout[t] = s;
        tout[t] = be_out[t] - rm_out[t] * s;
    }
    __syncthreads();
    if (t < REDD) {
        float a = 0.f;
        #pragma unroll 4
        for (int c = 0; c < CCH; ++c) a += se_w1[t * CCH + c] * ys[c];
        y1s[t] = a > 0.f ? a : SLOPE * a;
    }
    __syncthreads();
    float a = 0.f;
    #pragma unroll
    for (int r = 0; r < REDD; ++r) a += se_w2[t * REDD + r] * y1s[r];
    float sg = 1.f / (1.f + expf(-a));
    scale[b * CCH + t] = sg;
    rs[t] = sg * ymr;
    __syncthreads();
    const float* w = (t < INTR) ? (wq + t * CCH) : (wv + (t - INTR) * CCH);
    float a2 = 0.f;
    #pragma unroll 4
    for (int c = 0; c < CCH; ++c) a2 += w[c] * rs[c];
    if (t < INTR) qs[b * INTR + t] = a2;
    else          vs[b * INTR + (t - INTR)] = a2;
}

// ---------- 5a. Gram split-K, double-buffered DMA pipeline (2-phase template) ----------
__global__ __launch_bounds__(256) void gram_partial_kernel(const unsigned short* __restrict__ xh,
                                                           unsigned short* __restrict__ partials,
                                                           int nch) {
    __shared__ __align__(16) unsigned short Ah[2 * 128 * 64];  // 32 KB
    __shared__ __align__(16) unsigned short Bh[2 * 128 * 64];  // 32 KB
    int bid = blockIdx.x;
    int chunk = bid % nch;
    int t2 = bid / nch;
    int tile = t2 % 3;
    int b = t2 / 3;
    int rowbase = (tile == 1) ? 128 : 0;
    int colbase = (tile == 0) ? 0 : 128;
    bool diag = (tile < 2);
    const unsigned short* xb = xh + (size_t)b * CCH * NPIX;
    int kpb = NPIX / nch;
    int n0 = chunk * kpb;
    int nsteps = kpb >> 6;
    int tid = threadIdx.x;
    int l = tid & 63, w = tid >> 6;
    int wrow = (w >> 1) * 64, wcol = (w & 1) * 64;
    int sr = l >> 3, ssg = l & 7;

    f32x16 acc[2][2];
    #pragma unroll
    for (int i = 0; i < 2; ++i)
        #pragma unroll
        for (int j = 0; j < 2; ++j)
            #pragma unroll
            for (int r = 0; r < 16; ++r) acc[i][j][r] = 0.f;

    // prologue: stage step 0 into buffer 0
    {
        #pragma unroll
        for (int e = 0; e < 4; ++e) {
            int rbase = e * 32 + w * 8;
            int r = rbase + sr;
            int seg = ssg ^ (r & 7);
            gload_lds16(&xb[(size_t)(rowbase + r) * NPIX + n0 + seg * 8], &Ah[rbase * 64]);
            if (!diag)
                gload_lds16(&xb[(size_t)(colbase + r) * NPIX + n0 + seg * 8], &Bh[rbase * 64]);
        }
    }
    int cur = 0;
    for (int step = 0; step < nsteps; ++step) {
        __syncthreads();   // drains buf[cur] DMA; all waves done reading buf[cur^1]
        if (step + 1 < nsteps) {
            int kn = n0 + (step + 1) * 64;
            unsigned short* AhN = Ah + (cur ^ 1) * 8192;
            unsigned short* BhN = Bh + (cur ^ 1) * 8192;
            #pragma unroll
            for (int e = 0; e < 4; ++e) {
                int rbase = e * 32 + w * 8;
                int r = rbase + sr;
                int seg = ssg ^ (r & 7);
                gload_lds16(&xb[(size_t)(rowbase + r) * NPIX + kn + seg * 8], &AhN[rbase * 64]);
                if (!diag)
                    gload_lds16(&xb[(size_t)(colbase + r) * NPIX + kn + seg * 8], &BhN[rbase * 64]);
            }
        }
        const unsigned short* AP = Ah + cur * 8192;
        const unsigned short* BP = diag ? AP : (Bh + cur * 8192);
        #pragma unroll
        for (int kk = 0; kk < 4; ++kk) {
            int useg = kk * 2 + (l >> 5);
            f16x8 af[2], bf[2];
            #pragma unroll
            for (int at = 0; at < 2; ++at) {
                int r = wrow + at * 32 + (l & 31);
                af[at] = *(const f16x8*)&AP[r * 64 + ((useg ^ (r & 7)) << 3)];
            }
            #pragma unroll
            for (int bt = 0; bt < 2; ++bt) {
                int c = wcol + bt * 32 + (l & 31);
                bf[bt] = *(const f16x8*)&BP[c * 64 + ((useg ^ (c & 7)) << 3)];
            }
            #pragma unroll
            for (int at = 0; at < 2; ++at)
                #pragma unroll
                for (int bt = 0; bt < 2; ++bt)
                    acc[at][bt] = __builtin_amdgcn_mfma_f32_32x32x16_f16(af[at], bf[bt], acc[at][bt], 0, 0, 0);
        }
        cur ^= 1;
    }
    unsigned short* P = partials + (size_t)bid * (128 * 128);
    #pragma unroll
    for (int at = 0; at < 2; ++at)
        #pragma unroll
        for (int bt = 0; bt < 2; ++bt)
            #pragma unroll
            for (int r = 0; r < 16; ++r) {
                int lr = wrow + at * 32 + (r & 3) + ((r >> 2) << 3) + ((l >> 5) << 2);
                int lc = wcol + bt * 32 + (l & 31);
                P[lr * 128 + lc] = h1(acc[at][bt][r]);
            }
}

// ---------- 5b. reduce f16 partials -> G (f32) ----------
__global__ __launch_bounds__(256) void gram_reduce_kernel(const unsigned short* __restrict__ partials,
                                                          float* __restrict__ Gx,
                                                          int nch) {
    int bid = blockIdx.x;
    int part = bid & 15;
    int tileIdx = bid >> 4;
    int tile = tileIdx % 3;
    int b = tileIdx / 3;
    int rowbase = (tile == 1) ? 128 : 0;
    int colbase = (tile == 0) ? 0 : 128;
    int locIdx = part * 1024 + threadIdx.x * 4;
    const unsigned short* P = partials + (size_t)tileIdx * nch * (128 * 128) + locIdx;
    float4 s = make_float4(0.f, 0.f, 0.f, 0.f);
    for (int ch = 0; ch < nch; ++ch) {
        ushort4 v = *(const ushort4*)(P + (size_t)ch * (128 * 128));
        s.x += __half2float(__ushort_as_half(v.x));
        s.y += __half2float(__ushort_as_half(v.y));
        s.z += __half2float(__ushort_as_half(v.z));
        s.w += __half2float(__ushort_as_half(v.w));
    }
    int lr = locIdx >> 7, lc = locIdx & 127;
    float* G = Gx + (size_t)b * CCH * CCH;
    *(float4*)&G[(rowbase + lr) * CCH + colbase + lc] = s;
    if (tile == 2) {
        G[(colbase + lc + 0) * CCH + rowbase + lr] = s.x;
        G[(colbase + lc + 1) * CCH + rowbase + lr] = s.y;
        G[(colbase + lc + 2) * CCH + rowbase + lr] = s.z;
        G[(colbase + lc + 3) * CCH + rowbase + lr] = s.w;
    }
}

// ---------- 6+7 fused: T1 row -> S row -> softmax -> M[b,j,i] ----------
__global__ __launch_bounds__(256) void ts_kernel(const float* __restrict__ wq,
                                                 const float* __restrict__ scale,
                                                 const float* __restrict__ Gx,
                                                 const float* __restrict__ wv,
                                                 const float* __restrict__ bq,
                                                 const float* __restrict__ bv,
                                                 const float* __restrict__ qs,
                                                 const float* __restrict__ vs,
                                                 float* __restrict__ M) {
    int bid = blockIdx.x;
    int i = bid & 127, b = bid >> 7;
    int t = threadIdx.x;
    __shared__ float sw[CCH];
    __shared__ float t1s[CCH];
    __shared__ float part[256];
    __shared__ float redm[2], reds[2];
    sw[t] = wq[i * CCH + t] * scale[b * CCH + t];
    __syncthreads();
    const float* G = Gx + (size_t)b * CCH * CCH;
    float acc = 0.f;
    #pragma unroll 4
    for (int c = 0; c < CCH; ++c) acc += sw[c] * G[c * CCH + t];
    t1s[t] = acc * scale[b * CCH + t];
    __syncthreads();
    int j = t & 127, h = t >> 7;
    const float* wvr = wv + j * CCH + h * 128;
    const float* tp = t1s + h * 128;
    float p = 0.f;
    #pragma unroll 4
    for (int c = 0; c < 128; ++c) p += tp[c] * wvr[c];
    part[t] = p;
    __syncthreads();
    float acc2 = 0.f;
    if (t < 128)
        acc2 = part[t] + part[t + 128]
             + bq[i] * vs[b * INTR + j] + bv[j] * qs[b * INTR + i] + 16384.f * bq[i] * bv[j];
    float m = acc2;
    for (int off = 32; off > 0; off >>= 1) m = fmaxf(m, __shfl_xor(m, off));
    if (t == 0) redm[0] = m;
    if (t == 64) redm[1] = m;
    __syncthreads();
    m = fmaxf(redm[0], redm[1]);
    float e = expf(acc2 - m);
    float s = e;
    for (int off = 32; off > 0; off >>= 1) s += __shfl_xor(s, off);
    if (t == 0) reds[0] = s;
    if (t == 64) reds[1] = s;
    __syncthreads();
    s = reds[0] + reds[1];
    if (t < 128)
        M[(size_t)b * INTR * INTR + j * INTR + i] = e / s;   // transposed store
}

// ---------- 8-11 fused tail: M -> Wav -> W2 -> W7h (+bias chain -> b6), one block per batch ----------
__global__ __launch_bounds__(256) void tail_kernel(const float* __restrict__ M,
                                                   const float* __restrict__ wk,
                                                   const float* __restrict__ bk,
                                                   const float* __restrict__ wwg,
                                                   const float* __restrict__ swg,
                                                   const float* __restrict__ twg,
                                                   const float* __restrict__ wout,
                                                   const float* __restrict__ bout,
                                                   const float* __restrict__ sout,
                                                   const float* __restrict__ tout,
                                                   const float* __restrict__ scale,
                                                   unsigned short* __restrict__ W7h,
                                                   float* __restrict__ b6) {
    __shared__ __align__(16) unsigned short Bt[256 * 128];
    __shared__ __align__(16) unsigned short Ot[256 * 128];
    __shared__ float bavS[INTR], b2S[INTR], scS[CCH], soS[CCH], swgS[INTR];
    int b = blockIdx.x, tid = threadIdx.x;
    int l = tid & 63, w = tid >> 6;
    const float* Mb = M + (size_t)b * INTR * INTR;

    scS[tid] = scale[b * CCH + tid];
    soS[tid] = sout[tid];
    if (tid < INTR) swgS[tid] = swg[tid];

    {
        int mn = tid & 63;
        int mk0 = tid >> 6;
        #pragma unroll
        for (int e = 0; e < 8; ++e) {
            int j0 = (mk0 + 4 * e) * 4;
            int c0 = mn * 4;
            float4 q0 = *(const float4*)&wk[(size_t)(j0 + 0) * CCH + c0];
            float4 q1 = *(const float4*)&wk[(size_t)(j0 + 1) * CCH + c0];
            float4 q2 = *(const float4*)&wk[(size_t)(j0 + 2) * CCH + c0];
            float4 q3 = *(const float4*)&wk[(size_t)(j0 + 3) * CCH + c0];
            int unit = j0 >> 3, sub = (j0 >> 2) & 1;
            int key = (c0 >> 2) & 7;
            #pragma unroll
            for (int jj = 0; jj < 4; ++jj) {
                float e0 = jj == 0 ? q0.x : jj == 1 ? q0.y : jj == 2 ? q0.z : q0.w;
                float e1 = jj == 0 ? q1.x : jj == 1 ? q1.y : jj == 2 ? q1.z : q1.w;
                float e2 = jj == 0 ? q2.x : jj == 1 ? q2.y : jj == 2 ? q2.z : q2.w;
                float e3 = jj == 0 ? q3.x : jj == 1 ? q3.y : jj == 2 ? q3.z : q3.w;
                ushort4 cv = make_ushort4(h1(e0), h1(e1), h1(e2), h1(e3));
                *(ushort4*)&Bt[(c0 + jj) * 128 + ((unit ^ key) << 3) + sub * 4] = cv;
            }
        }
    }
    if (tid < INTR) {
        float a = 0.f;
        #pragma unroll 4
        for (int j = 0; j < INTR; ++j) a += Mb[tid * INTR + j] * bk[j];
        bavS[tid] = a;
    }
    __syncthreads();

    {
        f32x16 acc[4][2];
        #pragma unroll
        for (int at = 0; at < 4; ++at)
            #pragma unroll
            for (int bt = 0; bt < 2; ++bt)
                #pragma unroll
                for (int r = 0; r < 16; ++r) acc[at][bt][r] = 0.f;
        #pragma unroll
        for (int kk = 0; kk < 8; ++kk) {
            int useg = kk * 2 + (l >> 5);
            f16x8 bf[2];
            #pragma unroll
            for (int bt = 0; bt < 2; ++bt) {
                int c = w * 64 + bt * 32 + (l & 31);
                bf[bt] = *(const f16x8*)&Bt[c * 128 + ((useg ^ ((c >> 2) & 7)) << 3)];
            }
            #pragma unroll
            for (int at = 0; at < 4; ++at) {
                int i = at * 32 + (l & 31);
                float4 a0 = *(const float4*)&Mb[(size_t)i * INTR + useg * 8];
                float4 a1 = *(const float4*)&Mb[(size_t)i * INTR + useg * 8 + 4];
                f16x8 af = cvt8hf(a0, a1);
                #pragma unroll
                for (int bt = 0; bt < 2; ++bt)
                    acc[at][bt] = __builtin_amdgcn_mfma_f32_32x32x16_f16(af, bf[bt], acc[at][bt], 0, 0, 0);
            }
        }
        if (tid < INTR) {
            float a = 0.f;
            #pragma unroll 4
            for (int i = 0; i < INTR; ++i) a += wwg[tid * INTR + i] * bavS[i];
            b2S[tid] = swgS[tid] * a + twg[tid];
        }
        __syncthreads();
        #pragma unroll
        for (int at = 0; at < 4; ++at)
            #pragma unroll
            for (int bt = 0; bt < 2; ++bt)
                #pragma unroll
                for (int r = 0; r < 16; ++r) {
                    int i = at * 32 + (r & 3) + ((r >> 2) << 3) + ((l >> 5) << 2);
                    int c = w * 64 + bt * 32 + (l & 31);
                    Ot[c * 128 + (((i >> 3) ^ ((c >> 2) & 7)) << 3) + (i & 7)] = h1(acc[at][bt][r]);
                }
    }
    __syncthreads();

    {
        f32x16 acc[4][2];
        #pragma unroll
        for (int at = 0; at < 4; ++at)
            #pragma unroll
            for (int bt = 0; bt < 2; ++bt)
                #pragma unroll
                for (int r = 0; r < 16; ++r) acc[at][bt][r] = 0.f;
        #pragma unroll
        for (int kk = 0; kk < 8; ++kk) {
            int useg = kk * 2 + (l >> 5);
            f16x8 bf[2];
            #pragma unroll
            for (int bt = 0; bt < 2; ++bt) {
                int c = w * 64 + bt * 32 + (l & 31);
                bf[bt] = *(const f16x8*)&Ot[c * 128 + ((useg ^ ((c >> 2) & 7)) << 3)];
            }
            #pragma unroll
            for (int at = 0; at < 4; ++at) {
                int o = at * 32 + (l & 31);
                float4 a0 = *(const float4*)&wwg[(size_t)o * INTR + useg * 8];
                float4 a1 = *(const float4*)&wwg[(size_t)o * INTR + useg * 8 + 4];
                f16x8 af = cvt8hf(a0, a1);
                #pragma unroll
                for (int bt = 0; bt < 2; ++bt)
                    acc[at][bt] = __builtin_amdgcn_mfma_f32_32x32x16_f16(af, bf[bt], acc[at][bt], 0, 0, 0);
            }
        }
        {
            float a = 0.f;
            #pragma unroll 4
            for (int o = 0; o < INTR; ++o) a += wout[tid * INTR + o] * b2S[o];
            float b5 = a + bout[tid];
            b6[b * CCH + tid] = soS[tid] * b5 + tout[tid];
        }
        __syncthreads();
        #pragma unroll
        for (int at = 0; at < 4; ++at)
            #pragma unroll
            for (int bt = 0; bt < 2; ++bt)
                #pragma unroll
                for (int r = 0; r < 16; ++r) {
                    int o = at * 32 + (r & 3) + ((r >> 2) << 3) + ((l >> 5) << 2);
                    int c = w * 64 + bt * 32 + (l & 31);
                    Bt[c * 128 + (((o >> 3) ^ ((c >> 2) & 7)) << 3) + (o & 7)] = h1(swgS[o] * acc[at][bt][r]);
                }
    }
    __syncthreads();

    unsigned short* Wb = W7h + (size_t)b * CCH * CCH;
    #pragma unroll
    for (int p = 0; p < 2; ++p) {
        f32x16 acc[4][2];
        #pragma unroll
        for (int at = 0; at < 4; ++at)
            #pragma unroll
            for (int bt = 0; bt < 2; ++bt)
                #pragma unroll
                for (int r = 0; r < 16; ++r) acc[at][bt][r] = 0.f;
        #pragma unroll
        for (int kk = 0; kk < 8; ++kk) {
            int useg = kk * 2 + (l >> 5);
            f16x8 bf[2];
            #pragma unroll
            for (int bt = 0; bt < 2; ++bt) {
                int cp = w * 64 + bt * 32 + (l & 31);
                bf[bt] = *(const f16x8*)&Bt[cp * 128 + ((useg ^ ((cp >> 2) & 7)) << 3)];
            }
            #pragma unroll
            for (int at = 0; at < 4; ++at) {
                int cc = p * 128 + at * 32 + (l & 31);
                float4 a0 = *(const float4*)&wout[(size_t)cc * INTR + useg * 8];
                float4 a1 = *(const float4*)&wout[(size_t)cc * INTR + useg * 8 + 4];
                f16x8 af = cvt8hf(a0, a1);
                #pragma unroll
                for (int bt = 0; bt < 2; ++bt)
                    acc[at][bt] = __builtin_amdgcn_mfma_f32_32x32x16_f16(af, bf[bt], acc[at][bt], 0, 0, 0);
            }
        }
        #pragma unroll
        for (int at = 0; at < 4; ++at)
            #pragma unroll
            for (int bt = 0; bt < 2; ++bt)
                #pragma unroll
                for (int r = 0; r < 16; ++r) {
                    int c = p * 128 + at * 32 + (r & 3) + ((r >> 2) << 3) + ((l >> 5) << 2);
                    int cp = w * 64 + bt * 32 + (l & 31);
                    float w6 = soS[c] * acc[at][bt][r] + ((c == cp) ? 1.f : 0.f);
                    Wb[c * CCH + cp] = h1(w6 * scS[cp]);
                }
    }
}

// ---------- 12. final: R10 shape + dbuf Ws/Xs + T14 (issue-early / write-late) ----------
__device__ __forceinline__ void final_loadX(const unsigned short* xb, int k0, int n0,
                                            int mn, int mk0, ushort4 xq[2][4]) {
    #pragma unroll
    for (int mi = 0; mi < 2; ++mi) {
        int mk = mk0 + mi * 8;
        const unsigned short* sp = &xb[(size_t)(k0 + mk * 4) * NPIX + n0 + mn * 4];
        xq[mi][0] = *(const ushort4*)sp;
        xq[mi][1] = *(const ushort4*)(sp + NPIX);
        xq[mi][2] = *(const ushort4*)(sp + 2 * NPIX);
        xq[mi][3] = *(const ushort4*)(sp + 3 * NPIX);
    }
}

__device__ __forceinline__ void final_writeX(unsigned short* XsB, int mn, int mk0,
                                             const ushort4 xq[2][4]) {
    #pragma unroll
    for (int mi = 0; mi < 2; ++mi) {
        int mk = mk0 + mi * 8;
        ushort4 q0 = xq[mi][0], q1 = xq[mi][1], q2 = xq[mi][2], q3 = xq[mi][3];
        int klo = mk * 4;
        int unit = klo >> 3, sub = (klo & 7) >> 2;
        #pragma unroll
        for (int j = 0; j < 4; ++j) {
            unsigned short e0 = j == 0 ? q0.x : j == 1 ? q0.y : j == 2 ? q0.z : q0.w;
            unsigned short e1 = j == 0 ? q1.x : j == 1 ? q1.y : j == 2 ? q1.z : q1.w;
            unsigned short e2 = j == 0 ? q2.x : j == 1 ? q2.y : j == 2 ? q2.z : q2.w;
            unsigned short e3 = j == 0 ? q3.x : j == 1 ? q3.y : j == 2 ? q3.z : q3.w;
            int nl = mn * 4 + j;
            ushort4 cv = make_ushort4(e0, e1, e2, e3);
            int idx = nl * 64 + ((unit ^ ((nl >> 2) & 7)) << 3) + sub * 4;
            *(ushort4*)&XsB[idx] = cv;
        }
    }
}

__global__ __launch_bounds__(256) void final_mfma_kernel(const unsigned short* __restrict__ W7h,
                                                         const unsigned short* __restrict__ xh,
                                                         const float* __restrict__ b6,
                                                         float* __restrict__ out) {
    __shared__ __align__(16) unsigned short Ws[2 * 128 * 64];  // 32 KB
    __shared__ __align__(16) unsigned short Xs[2 * 128 * 64];  // 32 KB
    int bid0 = blockIdx.x;
    int bid = (bid0 & 7) * 256 + (bid0 >> 3);   // bijective XCD swizzle (2048 % 8 == 0)
    int ct = bid & 1;
    int nt = (bid >> 1) & 127;
    int b = bid >> 8;
    int cbase = ct * 128, n0 = nt * 128;
    const unsigned short* xb = xh + (size_t)b * CCH * NPIX;
    const unsigned short* Wb = W7h + (size_t)b * CCH * CCH;
    int tid = threadIdx.x;
    int l = tid & 63, w = tid >> 6;
    int wrow = (w >> 1) * 64, wcol = (w & 1) * 64;
    int mn = tid & 31, mk0 = tid >> 5;
    int sr = l >> 3, ssg = l & 7;

    f32x16 acc[2][2];
    #pragma unroll
    for (int i = 0; i < 2; ++i)
        #pragma unroll
        for (int j = 0; j < 2; ++j)
            #pragma unroll
            for (int r = 0; r < 16; ++r) acc[i][j][r] = 0.f;

    ushort4 xq[2][4];
    // prologue: stage step 0 into buffer 0
    {
        #pragma unroll
        for (int e = 0; e < 4; ++e) {
            int rbase = e * 32 + w * 8;
            int r = rbase + sr;
            int seg = ssg ^ (r & 7);
            gload_lds16(&Wb[(size_t)(cbase + r) * CCH + seg * 8], &Ws[rbase * 64]);
        }
        final_loadX(xb, 0, n0, mn, mk0, xq);
        final_writeX(Xs, mn, mk0, xq);
    }
    int cur = 0;
    for (int step = 0; step < 4; ++step) {
        __syncthreads();   // buf[cur] ready; all waves done with buf[cur^1]
        bool pf = (step < 3);
        int kn = (step + 1) * 64;
        if (pf) {
            // issue-early: DMA next W panel + next x loads (fly under MFMA phase)
            unsigned short* WsN = Ws + (cur ^ 1) * 8192;
            #pragma unroll
            for (int e = 0; e < 4; ++e) {
                int rbase = e * 32 + w * 8;
                int r = rbase + sr;
                int seg = ssg ^ (r & 7);
                gload_lds16(&Wb[(size_t)(cbase + r) * CCH + kn + seg * 8], &WsN[rbase * 64]);
            }
            final_loadX(xb, kn, n0, mn, mk0, xq);
        }
        const unsigned short* WsC = Ws + cur * 8192;
        const unsigned short* XsC = Xs + cur * 8192;
        #pragma unroll
        for (int kk = 0; kk < 4; ++kk) {
            int useg = kk * 2 + (l >> 5);
            f16x8 af[2], bfr[2];
            #pragma unroll
            for (int at = 0; at < 2; ++at) {
                int c = wrow + at * 32 + (l & 31);
                af[at] = *(const f16x8*)&WsC[c * 64 + ((useg ^ (c & 7)) << 3)];
            }
            #pragma unroll
            for (int bt = 0; bt < 2; ++bt) {
                int n = wcol + bt * 32 + (l & 31);
                bfr[bt] = *(const f16x8*)&XsC[n * 64 + ((useg ^ ((n >> 2) & 7)) << 3)];
            }
            #pragma unroll
            for (int at = 0; at < 2; ++at)
                #pragma unroll
                for (int bt = 0; bt < 2; ++bt)
                    acc[at][bt] = __builtin_amdgcn_mfma_f32_32x32x16_f16(af[at], bfr[bt], acc[at][bt], 0, 0, 0);
        }
        if (pf) final_writeX(Xs + (cur ^ 1) * 8192, mn, mk0, xq);  // write-late
        cur ^= 1;
    }
    #pragma unroll
    for (int at = 0; at < 2; ++at)
        #pragma unroll
        for (int bt = 0; bt < 2; ++bt)
            #pragma unroll
            for (int r = 0; r < 16; ++r) {
                int c = cbase + wrow + at * 32 + (r & 3) + ((r >> 2) << 3) + ((l >> 5) << 2);
                int n = n0 + wcol + bt * 32 + (l & 31);
                float v = acc[at][bt][r] + b6[b * CCH + c];
                v = v > 0.f ? v : SLOPE * v;
                out[(size_t)b * CCH * NPIX + (size_t)c * NPIX + n] = v;
            }
}

extern "C" void kernel_launch(void* const* d_in, const int* in_sizes, int n_in,
                              void* d_out, int out_size, void* d_ws, size_t ws_size,
                              hipStream_t stream) {
    (void)in_sizes; (void)n_in; (void)out_size;
    const float* x      = (const float*)d_in[0];
    const float* se_w1  = (const float*)d_in[1];
    const float* se_w2  = (const float*)d_in[2];
    const float* wq     = (const float*)d_in[3];
    const float* bq     = (const float*)d_in[4];
    const float* wk     = (const float*)d_in[5];
    const float* bk     = (const float*)d_in[6];
    const float* wv     = (const float*)d_in[7];
    const float* bv     = (const float*)d_in[8];
    const float* w_wg   = (const float*)d_in[9];
    const float* w_out  = (const float*)d_in[14];
    const float* b_out  = (const float*)d_in[15];
    float* out = (float*)d_out;
    float* ws = (float*)d_ws;
    unsigned short* xh = (unsigned short*)(ws + OFF_XH);

    size_t avail = ws_size / sizeof(float);
    int nch = 64;   // 1536 blocks = 3 exact rounds at 2 blocks/CU (64 KB LDS)
    while (nch > 1 && (size_t)OFF_PART + (size_t)NB * 3 * nch * 8192 > avail) nch >>= 1;

    cvtrow_kernel<<<NB * CCH, 256, 0, stream>>>(x, xh, ws + OFF_YM);
    gram_partial_kernel<<<NB * 3 * nch, 256, 0, stream>>>(xh, (unsigned short*)(ws + OFF_PART), nch);
    gram_reduce_kernel<<<NB * 3 * 16, 256, 0, stream>>>((const unsigned short*)(ws + OFF_PART),
                                                        ws + OFF_GX, nch);
    head_kernel<<<NB, 256, 0, stream>>>(ws + OFF_YM, se_w1, se_w2, wq, wv,
                                        (const float*)d_in[10], (const float*)d_in[11],
                                        (const float*)d_in[12], (const float*)d_in[13],
                                        (const float*)d_in[16], (const float*)d_in[17],
                                        (const float*)d_in[18], (const float*)d_in[19],
                                        ws + OFF_SC, ws + OFF_QS, ws + OFF_VS,
                                        ws + OFF_SWG, ws + OFF_TWG, ws + OFF_SOUT, ws + OFF_TOUT);
    ts_kernel<<<NB * INTR, 256, 0, stream>>>(wq, ws + OFF_SC, ws + OFF_GX, wv, bq, bv,
                                             ws + OFF_QS, ws + OFF_VS, ws + OFF_M);
    tail_kernel<<<NB, 256, 0, stream>>>(ws + OFF_M, wk, bk, w_wg, ws + OFF_SWG, ws + OFF_TWG,
                                        w_out, b_out, ws + OFF_SOUT, ws + OFF_TOUT, ws + OFF_SC,
                                        (unsigned short*)(ws + OFF_W7), ws + OFF_B6);
    final_mfma_kernel<<<NB * 2 * 128, 256, 0, stream>>>((const unsigned short*)(ws + OFF_W7),
                                                        xh, ws + OFF_B6, out);
}

// Round 13
// 241.187 us; speedup vs baseline: 1.0482x; 1.0482x over previous
//
#include <hip/hip_runtime.h>
#include <hip/hip_fp16.h>

#define NPIX 16384
#define CCH 256
#define INTR 128
#define REDD 32
#define NB 8
#define SLOPE 0.1f
#define BNEPS 1e-5f

typedef _Float16 f16x8 __attribute__((ext_vector_type(8)));
typedef __attribute__((ext_vector_type(16))) float f32x16;

// workspace offsets (floats)
#define OFF_GX    0            // 8*256*256 = 524288
#define OFF_YM    524288       // 2048 raw row sums (written by cvtrow)
#define OFF_SC    526336       // 2048
#define OFF_QS    530432       // 1024
#define OFF_VS    531456       // 1024
#define OFF_SWG   532480       // 128
#define OFF_TWG   532608       // 128
#define OFF_SOUT  532736       // 256
#define OFF_TOUT  532992       // 256
#define OFF_M     795392       // 8*128*128 = 131072
#define OFF_W7    1450752      // ushort f16 [8*256*256] = 1 MB
#define OFF_B6    1975040      // 2048 -> ends 1977088
#define OFF_XH    1977088      // ushort f16 x [8*256*16384] = 64 MB
#define OFF_PART  18754304     // f16 partials: NB*3*nch*16384 shorts (nch=32)

__device__ __forceinline__ unsigned short h1(float f) {
    __half h = __float2half(f);
    return __half_as_ushort(h);
}

__device__ __forceinline__ uint4 cvt8h(const float4 a, const float4 c) {
    __half2 p0 = __floats2half2_rn(a.x, a.y);
    __half2 p1 = __floats2half2_rn(a.z, a.w);
    __half2 p2 = __floats2half2_rn(c.x, c.y);
    __half2 p3 = __floats2half2_rn(c.z, c.w);
    uint4 r;
    r.x = *(unsigned int*)&p0; r.y = *(unsigned int*)&p1;
    r.z = *(unsigned int*)&p2; r.w = *(unsigned int*)&p3;
    return r;
}

__device__ __forceinline__ f16x8 cvt8hf(const float4 a, const float4 c) {
    uint4 u = cvt8h(a, c);
    return *(f16x8*)&u;
}

__device__ __forceinline__ void gload_lds16(const void* g, void* l) {
    __builtin_amdgcn_global_load_lds((const __attribute__((address_space(1))) void*)g,
                                     (__attribute__((address_space(3))) void*)l, 16, 0, 0);
}

// ---------- 1. x f32 -> xh f16 (once) + fused row sums ----------
__global__ __launch_bounds__(256) void cvtrow_kernel(const float* __restrict__ x,
                                                     unsigned short* __restrict__ xh,
                                                     float* __restrict__ ymsum) {
    int row = blockIdx.x;  // b*256 + c
    const float4* p4 = (const float4*)(x + (size_t)row * NPIX);
    uint4* o4 = (uint4*)(xh + (size_t)row * NPIX);
    float s = 0.f;
    for (int i = threadIdx.x; i < NPIX / 8; i += 256) {
        float4 v0 = p4[2 * i];
        float4 v1 = p4[2 * i + 1];
        s += (v0.x + v0.y) + (v0.z + v0.w) + (v1.x + v1.y) + (v1.z + v1.w);
        o4[i] = cvt8h(v0, v1);
    }
    for (int off = 32; off > 0; off >>= 1) s += __shfl_xor(s, off);
    __shared__ float red[4];
    if ((threadIdx.x & 63) == 0) red[threadIdx.x >> 6] = s;
    __syncthreads();
    if (threadIdx.x == 0)
        ymsum[row] = red[0] + red[1] + red[2] + red[3];
}

// ---------- 2. head: SE + BN-prep + qs/vs, fused ----------
__global__ __launch_bounds__(256) void head_kernel(const float* __restrict__ ymsum,
                                                   const float* __restrict__ se_w1,
                                                   const float* __restrict__ se_w2,
                                                   const float* __restrict__ wq,
                                                   const float* __restrict__ wv,
                                                   const float* __restrict__ g_wg, const float* __restrict__ be_wg,
                                                   const float* __restrict__ rm_wg, const float* __restrict__ rv_wg,
                                                   const float* __restrict__ g_out, const float* __restrict__ be_out,
                                                   const float* __restrict__ rm_out, const float* __restrict__ rv_out,
                                                   float* __restrict__ scale,
                                                   float* __restrict__ qs, float* __restrict__ vs,
                                                   float* __restrict__ swg, float* __restrict__ twg,
                                                   float* __restrict__ sout, float* __restrict__ tout) {
    int b = blockIdx.x, t = threadIdx.x;
    __shared__ float ys[CCH], y1s[REDD], rs[CCH];
    float ymr = ymsum[b * CCH + t];
    ys[t] = ymr * (1.f / 16384.f);
    if (b == 0) {
        if (t < INTR) {
            float s = g_wg[t] / sqrtf(rv_wg[t] + BNEPS);
            swg[t] = s;
            twg[t] = be_wg[t] - rm_wg[t] * s;
        }
        float s = g_out[t] / sqrtf(rv_out[t] + BNEPS);
        sout[t] = s;
        tout[t] = be_out[t] - rm_out[t] * s;
    }
    __syncthreads();
    if (t < REDD) {
        float a = 0.f;
        #pragma unroll 4
        for (int c = 0; c < CCH; ++c) a += se_w1[t * CCH + c] * ys[c];
        y1s[t] = a > 0.f ? a : SLOPE * a;
    }
    __syncthreads();
    float a = 0.f;
    #pragma unroll
    for (int r = 0; r < REDD; ++r) a += se_w2[t * REDD + r] * y1s[r];
    float sg = 1.f / (1.f + expf(-a));
    scale[b * CCH + t] = sg;
    rs[t] = sg * ymr;
    __syncthreads();
    const float* w = (t < INTR) ? (wq + t * CCH) : (wv + (t - INTR) * CCH);
    float a2 = 0.f;
    #pragma unroll 4
    for (int c = 0; c < CCH; ++c) a2 += w[c] * rs[c];
    if (t < INTR) qs[b * INTR + t] = a2;
    else          vs[b * INTR + (t - INTR)] = a2;
}

// ---------- 5a. Gram split-K: R10 structure; diag tiles get zero-cost dbuf (Bh unused) ----------
__global__ __launch_bounds__(256) void gram_partial_kernel(const unsigned short* __restrict__ xh,
                                                           unsigned short* __restrict__ partials,
                                                           int nch) {
    __shared__ __align__(16) unsigned short Ah[128 * 64];   // diag: buf0 ; off-diag: A panel
    __shared__ __align__(16) unsigned short Bh[128 * 64];   // diag: buf1 ; off-diag: B panel
    int bid = blockIdx.x;
    int chunk = bid % nch;
    int t2 = bid / nch;
    int tile = t2 % 3;
    int b = t2 / 3;
    int rowbase = (tile == 1) ? 128 : 0;
    int colbase = (tile == 0) ? 0 : 128;
    bool diag = (tile < 2);
    const unsigned short* xb = xh + (size_t)b * CCH * NPIX;
    int kpb = NPIX / nch;
    int n0 = chunk * kpb;
    int nsteps = kpb >> 6;
    int tid = threadIdx.x;
    int l = tid & 63, w = tid >> 6;
    int wrow = (w >> 1) * 64, wcol = (w & 1) * 64;
    int sr = l >> 3, ssg = l & 7;

    f32x16 acc[2][2];
    #pragma unroll
    for (int i = 0; i < 2; ++i)
        #pragma unroll
        for (int j = 0; j < 2; ++j)
            #pragma unroll
            for (int r = 0; r < 16; ++r) acc[i][j][r] = 0.f;

    if (diag) {
        // double-buffer Ah/Bh: ONE barrier/step, DMA flies under MFMA. Same LDS as R10.
        #pragma unroll
        for (int e = 0; e < 4; ++e) {
            int rbase = e * 32 + w * 8;
            int r = rbase + sr;
            int seg = ssg ^ (r & 7);
            gload_lds16(&xb[(size_t)(rowbase + r) * NPIX + n0 + seg * 8], &Ah[rbase * 64]);
        }
        for (int step = 0; step < nsteps; ++step) {
            __syncthreads();   // drains this step's DMA; prev MFMA reads done block-wide
            unsigned short* curB = (step & 1) ? Bh : Ah;
            unsigned short* nxtB = (step & 1) ? Ah : Bh;
            if (step + 1 < nsteps) {
                int kn = n0 + (step + 1) * 64;
                #pragma unroll
                for (int e = 0; e < 4; ++e) {
                    int rbase = e * 32 + w * 8;
                    int r = rbase + sr;
                    int seg = ssg ^ (r & 7);
                    gload_lds16(&xb[(size_t)(rowbase + r) * NPIX + kn + seg * 8], &nxtB[rbase * 64]);
                }
            }
            #pragma unroll
            for (int kk = 0; kk < 4; ++kk) {
                int useg = kk * 2 + (l >> 5);
                f16x8 af[2], bf[2];
                #pragma unroll
                for (int at = 0; at < 2; ++at) {
                    int r = wrow + at * 32 + (l & 31);
                    af[at] = *(const f16x8*)&curB[r * 64 + ((useg ^ (r & 7)) << 3)];
                }
                #pragma unroll
                for (int bt = 0; bt < 2; ++bt) {
                    int c = wcol + bt * 32 + (l & 31);
                    bf[bt] = *(const f16x8*)&curB[c * 64 + ((useg ^ (c & 7)) << 3)];
                }
                #pragma unroll
                for (int at = 0; at < 2; ++at)
                    #pragma unroll
                    for (int bt = 0; bt < 2; ++bt)
                        acc[at][bt] = __builtin_amdgcn_mfma_f32_32x32x16_f16(af[at], bf[bt], acc[at][bt], 0, 0, 0);
            }
        }
    } else {
        // off-diag: R10 path verbatim (2 barriers/step, both panels staged)
        for (int step = 0; step < nsteps; ++step) {
            int k0 = n0 + step * 64;
            __syncthreads();
            #pragma unroll
            for (int e = 0; e < 4; ++e) {
                int rbase = e * 32 + w * 8;
                int r = rbase + sr;
                int seg = ssg ^ (r & 7);
                gload_lds16(&xb[(size_t)(rowbase + r) * NPIX + k0 + seg * 8], &Ah[rbase * 64]);
                gload_lds16(&xb[(size_t)(colbase + r) * NPIX + k0 + seg * 8], &Bh[rbase * 64]);
            }
            __syncthreads();
            #pragma unroll
            for (int kk = 0; kk < 4; ++kk) {
                int useg = kk * 2 + (l >> 5);
                f16x8 af[2], bf[2];
                #pragma unroll
                for (int at = 0; at < 2; ++at) {
                    int r = wrow + at * 32 + (l & 31);
                    af[at] = *(const f16x8*)&Ah[r * 64 + ((useg ^ (r & 7)) << 3)];
                }
                #pragma unroll
                for (int bt = 0; bt < 2; ++bt) {
                    int c = wcol + bt * 32 + (l & 31);
                    bf[bt] = *(const f16x8*)&Bh[c * 64 + ((useg ^ (c & 7)) << 3)];
                }
                #pragma unroll
                for (int at = 0; at < 2; ++at)
                    #pragma unroll
                    for (int bt = 0; bt < 2; ++bt)
                        acc[at][bt] = __builtin_amdgcn_mfma_f32_32x32x16_f16(af[at], bf[bt], acc[at][bt], 0, 0, 0);
            }
        }
    }
    unsigned short* P = partials + (size_t)bid * (128 * 128);
    #pragma unroll
    for (int at = 0; at < 2; ++at)
        #pragma unroll
        for (int bt = 0; bt < 2; ++bt)
            #pragma unroll
            for (int r = 0; r < 16; ++r) {
                int lr = wrow + at * 32 + (r & 3) + ((r >> 2) << 3) + ((l >> 5) << 2);
                int lc = wcol + bt * 32 + (l & 31);
                P[lr * 128 + lc] = h1(acc[at][bt][r]);
            }
}

// ---------- 5b. reduce f16 partials -> G (f32) ----------
__global__ __launch_bounds__(256) void gram_reduce_kernel(const unsigned short* __restrict__ partials,
                                                          float* __restrict__ Gx,
                                                          int nch) {
    int bid = blockIdx.x;
    int part = bid & 15;
    int tileIdx = bid >> 4;
    int tile = tileIdx % 3;
    int b = tileIdx / 3;
    int rowbase = (tile == 1) ? 128 : 0;
    int colbase = (tile == 0) ? 0 : 128;
    int locIdx = part * 1024 + threadIdx.x * 4;
    const unsigned short* P = partials + (size_t)tileIdx * nch * (128 * 128) + locIdx;
    float4 s = make_float4(0.f, 0.f, 0.f, 0.f);
    for (int ch = 0; ch < nch; ++ch) {
        ushort4 v = *(const ushort4*)(P + (size_t)ch * (128 * 128));
        s.x += __half2float(__ushort_as_half(v.x));
        s.y += __half2float(__ushort_as_half(v.y));
        s.z += __half2float(__ushort_as_half(v.z));
        s.w += __half2float(__ushort_as_half(v.w));
    }
    int lr = locIdx >> 7, lc = locIdx & 127;
    float* G = Gx + (size_t)b * CCH * CCH;
    *(float4*)&G[(rowbase + lr) * CCH + colbase + lc] = s;
    if (tile == 2) {
        G[(colbase + lc + 0) * CCH + rowbase + lr] = s.x;
        G[(colbase + lc + 1) * CCH + rowbase + lr] = s.y;
        G[(colbase + lc + 2) * CCH + rowbase + lr] = s.z;
        G[(colbase + lc + 3) * CCH + rowbase + lr] = s.w;
    }
}

// ---------- 6+7 fused: T1 row -> S row -> softmax -> M[b,j,i] ----------
__global__ __launch_bounds__(256) void ts_kernel(const float* __restrict__ wq,
                                                 const float* __restrict__ scale,
                                                 const float* __restrict__ Gx,
                                                 const float* __restrict__ wv,
                                                 const float* __restrict__ bq,
                                                 const float* __restrict__ bv,
                                                 const float* __restrict__ qs,
                                                 const float* __restrict__ vs,
                                                 float* __restrict__ M) {
    int bid = blockIdx.x;
    int i = bid & 127, b = bid >> 7;
    int t = threadIdx.x;
    __shared__ float sw[CCH];
    __shared__ float t1s[CCH];
    __shared__ float part[256];
    __shared__ float redm[2], reds[2];
    sw[t] = wq[i * CCH + t] * scale[b * CCH + t];
    __syncthreads();
    const float* G = Gx + (size_t)b * CCH * CCH;
    float acc = 0.f;
    #pragma unroll 4
    for (int c = 0; c < CCH; ++c) acc += sw[c] * G[c * CCH + t];
    t1s[t] = acc * scale[b * CCH + t];
    __syncthreads();
    int j = t & 127, h = t >> 7;
    const float* wvr = wv + j * CCH + h * 128;
    const float* tp = t1s + h * 128;
    float p = 0.f;
    #pragma unroll 4
    for (int c = 0; c < 128; ++c) p += tp[c] * wvr[c];
    part[t] = p;
    __syncthreads();
    float acc2 = 0.f;
    if (t < 128)
        acc2 = part[t] + part[t + 128]
             + bq[i] * vs[b * INTR + j] + bv[j] * qs[b * INTR + i] + 16384.f * bq[i] * bv[j];
    float m = acc2;
    for (int off = 32; off > 0; off >>= 1) m = fmaxf(m, __shfl_xor(m, off));
    if (t == 0) redm[0] = m;
    if (t == 64) redm[1] = m;
    __syncthreads();
    m = fmaxf(redm[0], redm[1]);
    float e = expf(acc2 - m);
    float s = e;
    for (int off = 32; off > 0; off >>= 1) s += __shfl_xor(s, off);
    if (t == 0) reds[0] = s;
    if (t == 64) reds[1] = s;
    __syncthreads();
    s = reds[0] + reds[1];
    if (t < 128)
        M[(size_t)b * INTR * INTR + j * INTR + i] = e / s;   // transposed store
}

// ---------- 8-11 fused tail: M -> Wav -> W2 -> W7h (+bias chain -> b6), one block per batch ----------
__global__ __launch_bounds__(256) void tail_kernel(const float* __restrict__ M,
                                                   const float* __restrict__ wk,
                                                   const float* __restrict__ bk,
                                                   const float* __restrict__ wwg,
                                                   const float* __restrict__ swg,
                                                   const float* __restrict__ twg,
                                                   const float* __restrict__ wout,
                                                   const float* __restrict__ bout,
                                                   const float* __restrict__ sout,
                                                   const float* __restrict__ tout,
                                                   const float* __restrict__ scale,
                                                   unsigned short* __restrict__ W7h,
                                                   float* __restrict__ b6) {
    __shared__ __align__(16) unsigned short Bt[256 * 128];
    __shared__ __align__(16) unsigned short Ot[256 * 128];
    __shared__ float bavS[INTR], b2S[INTR], scS[CCH], soS[CCH], swgS[INTR];
    int b = blockIdx.x, tid = threadIdx.x;
    int l = tid & 63, w = tid >> 6;
    const float* Mb = M + (size_t)b * INTR * INTR;

    scS[tid] = scale[b * CCH + tid];
    soS[tid] = sout[tid];
    if (tid < INTR) swgS[tid] = swg[tid];

    {
        int mn = tid & 63;
        int mk0 = tid >> 6;
        #pragma unroll
        for (int e = 0; e < 8; ++e) {
            int j0 = (mk0 + 4 * e) * 4;
            int c0 = mn * 4;
            float4 q0 = *(const float4*)&wk[(size_t)(j0 + 0) * CCH + c0];
            float4 q1 = *(const float4*)&wk[(size_t)(j0 + 1) * CCH + c0];
            float4 q2 = *(const float4*)&wk[(size_t)(j0 + 2) * CCH + c0];
            float4 q3 = *(const float4*)&wk[(size_t)(j0 + 3) * CCH + c0];
            int unit = j0 >> 3, sub = (j0 >> 2) & 1;
            int key = (c0 >> 2) & 7;
            #pragma unroll
            for (int jj = 0; jj < 4; ++jj) {
                float e0 = jj == 0 ? q0.x : jj == 1 ? q0.y : jj == 2 ? q0.z : q0.w;
                float e1 = jj == 0 ? q1.x : jj == 1 ? q1.y : jj == 2 ? q1.z : q1.w;
                float e2 = jj == 0 ? q2.x : jj == 1 ? q2.y : jj == 2 ? q2.z : q2.w;
                float e3 = jj == 0 ? q3.x : jj == 1 ? q3.y : jj == 2 ? q3.z : q3.w;
                ushort4 cv = make_ushort4(h1(e0), h1(e1), h1(e2), h1(e3));
                *(ushort4*)&Bt[(c0 + jj) * 128 + ((unit ^ key) << 3) + sub * 4] = cv;
            }
        }
    }
    if (tid < INTR) {
        float a = 0.f;
        #pragma unroll 4
        for (int j = 0; j < INTR; ++j) a += Mb[tid * INTR + j] * bk[j];
        bavS[tid] = a;
    }
    __syncthreads();

    {
        f32x16 acc[4][2];
        #pragma unroll
        for (int at = 0; at < 4; ++at)
            #pragma unroll
            for (int bt = 0; bt < 2; ++bt)
                #pragma unroll
                for (int r = 0; r < 16; ++r) acc[at][bt][r] = 0.f;
        #pragma unroll
        for (int kk = 0; kk < 8; ++kk) {
            int useg = kk * 2 + (l >> 5);
            f16x8 bf[2];
            #pragma unroll
            for (int bt = 0; bt < 2; ++bt) {
                int c = w * 64 + bt * 32 + (l & 31);
                bf[bt] = *(const f16x8*)&Bt[c * 128 + ((useg ^ ((c >> 2) & 7)) << 3)];
            }
            #pragma unroll
            for (int at = 0; at < 4; ++at) {
                int i = at * 32 + (l & 31);
                float4 a0 = *(const float4*)&Mb[(size_t)i * INTR + useg * 8];
                float4 a1 = *(const float4*)&Mb[(size_t)i * INTR + useg * 8 + 4];
                f16x8 af = cvt8hf(a0, a1);
                #pragma unroll
                for (int bt = 0; bt < 2; ++bt)
                    acc[at][bt] = __builtin_amdgcn_mfma_f32_32x32x16_f16(af, bf[bt], acc[at][bt], 0, 0, 0);
            }
        }
        if (tid < INTR) {
            float a = 0.f;
            #pragma unroll 4
            for (int i = 0; i < INTR; ++i) a += wwg[tid * INTR + i] * bavS[i];
            b2S[tid] = swgS[tid] * a + twg[tid];
        }
        __syncthreads();
        #pragma unroll
        for (int at = 0; at < 4; ++at)
            #pragma unroll
            for (int bt = 0; bt < 2; ++bt)
                #pragma unroll
                for (int r = 0; r < 16; ++r) {
                    int i = at * 32 + (r & 3) + ((r >> 2) << 3) + ((l >> 5) << 2);
                    int c = w * 64 + bt * 32 + (l & 31);
                    Ot[c * 128 + (((i >> 3) ^ ((c >> 2) & 7)) << 3) + (i & 7)] = h1(acc[at][bt][r]);
                }
    }
    __syncthreads();

    {
        f32x16 acc[4][2];
        #pragma unroll
        for (int at = 0; at < 4; ++at)
            #pragma unroll
            for (int bt = 0; bt < 2; ++bt)
                #pragma unroll
                for (int r = 0; r < 16; ++r) acc[at][bt][r] = 0.f;
        #pragma unroll
        for (int kk = 0; kk < 8; ++kk) {
            int useg = kk * 2 + (l >> 5);
            f16x8 bf[2];
            #pragma unroll
            for (int bt = 0; bt < 2; ++bt) {
                int c = w * 64 + bt * 32 + (l & 31);
                bf[bt] = *(const f16x8*)&Ot[c * 128 + ((useg ^ ((c >> 2) & 7)) << 3)];
            }
            #pragma unroll
            for (int at = 0; at < 4; ++at) {
                int o = at * 32 + (l & 31);
                float4 a0 = *(const float4*)&wwg[(size_t)o * INTR + useg * 8];
                float4 a1 = *(const float4*)&wwg[(size_t)o * INTR + useg * 8 + 4];
                f16x8 af = cvt8hf(a0, a1);
                #pragma unroll
                for (int bt = 0; bt < 2; ++bt)
                    acc[at][bt] = __builtin_amdgcn_mfma_f32_32x32x16_f16(af, bf[bt], acc[at][bt], 0, 0, 0);
            }
        }
        {
            float a = 0.f;
            #pragma unroll 4
            for (int o = 0; o < INTR; ++o) a += wout[tid * INTR + o] * b2S[o];
            float b5 = a + bout[tid];
            b6[b * CCH + tid] = soS[tid] * b5 + tout[tid];
        }
        __syncthreads();
        #pragma unroll
        for (int at = 0; at < 4; ++at)
            #pragma unroll
            for (int bt = 0; bt < 2; ++bt)
                #pragma unroll
                for (int r = 0; r < 16; ++r) {
                    int o = at * 32 + (r & 3) + ((r >> 2) << 3) + ((l >> 5) << 2);
                    int c = w * 64 + bt * 32 + (l & 31);
                    Bt[c * 128 + (((o >> 3) ^ ((c >> 2) & 7)) << 3) + (o & 7)] = h1(swgS[o] * acc[at][bt][r]);
                }
    }
    __syncthreads();

    unsigned short* Wb = W7h + (size_t)b * CCH * CCH;
    #pragma unroll
    for (int p = 0; p < 2; ++p) {
        f32x16 acc[4][2];
        #pragma unroll
        for (int at = 0; at < 4; ++at)
            #pragma unroll
            for (int bt = 0; bt < 2; ++bt)
                #pragma unroll
                for (int r = 0; r < 16; ++r) acc[at][bt][r] = 0.f;
        #pragma unroll
        for (int kk = 0; kk < 8; ++kk) {
            int useg = kk * 2 + (l >> 5);
            f16x8 bf[2];
            #pragma unroll
            for (int bt = 0; bt < 2; ++bt) {
                int cp = w * 64 + bt * 32 + (l & 31);
                bf[bt] = *(const f16x8*)&Bt[cp * 128 + ((useg ^ ((cp >> 2) & 7)) << 3)];
            }
            #pragma unroll
            for (int at = 0; at < 4; ++at) {
                int cc = p * 128 + at * 32 + (l & 31);
                float4 a0 = *(const float4*)&wout[(size_t)cc * INTR + useg * 8];
                float4 a1 = *(const float4*)&wout[(size_t)cc * INTR + useg * 8 + 4];
                f16x8 af = cvt8hf(a0, a1);
                #pragma unroll
                for (int bt = 0; bt < 2; ++bt)
                    acc[at][bt] = __builtin_amdgcn_mfma_f32_32x32x16_f16(af, bf[bt], acc[at][bt], 0, 0, 0);
            }
        }
        #pragma unroll
        for (int at = 0; at < 4; ++at)
            #pragma unroll
            for (int bt = 0; bt < 2; ++bt)
                #pragma unroll
                for (int r = 0; r < 16; ++r) {
                    int c = p * 128 + at * 32 + (r & 3) + ((r >> 2) << 3) + ((l >> 5) << 2);
                    int cp = w * 64 + bt * 32 + (l & 31);
                    float w6 = soS[c] * acc[at][bt][r] + ((c == cp) ? 1.f : 0.f);
                    Wb[c * CCH + cp] = h1(w6 * scS[cp]);
                }
    }
}

// ---------- 12. out = leaky(W7 @ xh + b6), R10 version (XCD-swizzled, gload_lds W) ----------
__global__ __launch_bounds__(256, 4) void final_mfma_kernel(const unsigned short* __restrict__ W7h,
                                                            const unsigned short* __restrict__ xh,
                                                            const float* __restrict__ b6,
                                                            float* __restrict__ out) {
    __shared__ __align__(16) unsigned short Ws[128 * 64];
    __shared__ __align__(16) unsigned short Xs[128 * 64];
    int bid0 = blockIdx.x;
    int bid = (bid0 & 7) * 256 + (bid0 >> 3);   // bijective XCD swizzle (2048 % 8 == 0)
    int ct = bid & 1;
    int nt = (bid >> 1) & 127;
    int b = bid >> 8;
    int cbase = ct * 128, n0 = nt * 128;
    const unsigned short* xb = xh + (size_t)b * CCH * NPIX;
    const unsigned short* Wb = W7h + (size_t)b * CCH * CCH;
    int tid = threadIdx.x;
    int l = tid & 63, w = tid >> 6;
    int wrow = (w >> 1) * 64, wcol = (w & 1) * 64;
    int mn = tid & 31, mk0 = tid >> 5;
    int sr = l >> 3, ssg = l & 7;

    f32x16 acc[2][2];
    #pragma unroll
    for (int i = 0; i < 2; ++i)
        #pragma unroll
        for (int j = 0; j < 2; ++j)
            #pragma unroll
            for (int r = 0; r < 16; ++r) acc[i][j][r] = 0.f;

    for (int step = 0; step < 4; ++step) {
        int k0 = step * 64;
        __syncthreads();
        #pragma unroll
        for (int e = 0; e < 4; ++e) {
            int rbase = e * 32 + w * 8;
            int r = rbase + sr;
            int seg = ssg ^ (r & 7);
            gload_lds16(&Wb[(size_t)(cbase + r) * CCH + k0 + seg * 8], &Ws[rbase * 64]);
        }
        #pragma unroll
        for (int mi = 0; mi < 2; ++mi) {
            int mk = mk0 + mi * 8;
            const unsigned short* sp = &xb[(size_t)(k0 + mk * 4) * NPIX + n0 + mn * 4];
            ushort4 q0 = *(const ushort4*)sp;
            ushort4 q1 = *(const ushort4*)(sp + NPIX);
            ushort4 q2 = *(const ushort4*)(sp + 2 * NPIX);
            ushort4 q3 = *(const ushort4*)(sp + 3 * NPIX);
            int klo = mk * 4;
            int unit = klo >> 3, sub = (klo & 7) >> 2;
            #pragma unroll
            for (int j = 0; j < 4; ++j) {
                unsigned short e0 = j == 0 ? q0.x : j == 1 ? q0.y : j == 2 ? q0.z : q0.w;
                unsigned short e1 = j == 0 ? q1.x : j == 1 ? q1.y : j == 2 ? q1.z : q1.w;
                unsigned short e2 = j == 0 ? q2.x : j == 1 ? q2.y : j == 2 ? q2.z : q2.w;
                unsigned short e3 = j == 0 ? q3.x : j == 1 ? q3.y : j == 2 ? q3.z : q3.w;
                int nl = mn * 4 + j;
                ushort4 cv = make_ushort4(e0, e1, e2, e3);
                int idx = nl * 64 + ((unit ^ ((nl >> 2) & 7)) << 3) + sub * 4;
                *(ushort4*)&Xs[idx] = cv;
            }
        }
        __syncthreads();
        #pragma unroll
        for (int kk = 0; kk < 4; ++kk) {
            int useg = kk * 2 + (l >> 5);
            f16x8 af[2], bfr[2];
            #pragma unroll
            for (int at = 0; at < 2; ++at) {
                int c = wrow + at * 32 + (l & 31);
                af[at] = *(const f16x8*)&Ws[c * 64 + ((useg ^ (c & 7)) << 3)];
            }
            #pragma unroll
            for (int bt = 0; bt < 2; ++bt) {
                int n = wcol + bt * 32 + (l & 31);
                bfr[bt] = *(const f16x8*)&Xs[n * 64 + ((useg ^ ((n >> 2) & 7)) << 3)];
            }
            #pragma unroll
            for (int at = 0; at < 2; ++at)
                #pragma unroll
                for (int bt = 0; bt < 2; ++bt)
                    acc[at][bt] = __builtin_amdgcn_mfma_f32_32x32x16_f16(af[at], bfr[bt], acc[at][bt], 0, 0, 0);
        }
    }
    #pragma unroll
    for (int at = 0; at < 2; ++at)
        #pragma unroll
        for (int bt = 0; bt < 2; ++bt)
            #pragma unroll
            for (int r = 0; r < 16; ++r) {
                int c = cbase + wrow + at * 32 + (r & 3) + ((r >> 2) << 3) + ((l >> 5) << 2);
                int n = n0 + wcol + bt * 32 + (l & 31);
                float v = acc[at][bt][r] + b6[b * CCH + c];
                v = v > 0.f ? v : SLOPE * v;
                out[(size_t)b * CCH * NPIX + (size_t)c * NPIX + n] = v;
            }
}

extern "C" void kernel_launch(void* const* d_in, const int* in_sizes, int n_in,
                              void* d_out, int out_size, void* d_ws, size_t ws_size,
                              hipStream_t stream) {
    (void)in_sizes; (void)n_in; (void)out_size;
    const float* x      = (const float*)d_in[0];
    const float* se_w1  = (const float*)d_in[1];
    const float* se_w2  = (const float*)d_in[2];
    const float* wq     = (const float*)d_in[3];
    const float* bq     = (const float*)d_in[4];
    const float* wk     = (const float*)d_in[5];
    const float* bk     = (const float*)d_in[6];
    const float* wv     = (const float*)d_in[7];
    const float* bv     = (const float*)d_in[8];
    const float* w_wg   = (const float*)d_in[9];
    const float* w_out  = (const float*)d_in[14];
    const float* b_out  = (const float*)d_in[15];
    float* out = (float*)d_out;
    float* ws = (float*)d_ws;
    unsigned short* xh = (unsigned short*)(ws + OFF_XH);

    size_t avail = ws_size / sizeof(float);
    int nch = 32;
    while (nch > 1 && (size_t)OFF_PART + (size_t)NB * 3 * nch * 8192 > avail) nch >>= 1;

    cvtrow_kernel<<<NB * CCH, 256, 0, stream>>>(x, xh, ws + OFF_YM);
    gram_partial_kernel<<<NB * 3 * nch, 256, 0, stream>>>(xh, (unsigned short*)(ws + OFF_PART), nch);
    gram_reduce_kernel<<<NB * 3 * 16, 256, 0, stream>>>((const unsigned short*)(ws + OFF_PART),
                                                        ws + OFF_GX, nch);
    head_kernel<<<NB, 256, 0, stream>>>(ws + OFF_YM, se_w1, se_w2, wq, wv,
                                        (const float*)d_in[10], (const float*)d_in[11],
                                        (const float*)d_in[12], (const float*)d_in[13],
                                        (const float*)d_in[16], (const float*)d_in[17],
                                        (const float*)d_in[18], (const float*)d_in[19],
                                        ws + OFF_SC, ws + OFF_QS, ws + OFF_VS,
                                        ws + OFF_SWG, ws + OFF_TWG, ws + OFF_SOUT, ws + OFF_TOUT);
    ts_kernel<<<NB * INTR, 256, 0, stream>>>(wq, ws + OFF_SC, ws + OFF_GX, wv, bq, bv,
                                             ws + OFF_QS, ws + OFF_VS, ws + OFF_M);
    tail_kernel<<<NB, 256, 0, stream>>>(ws + OFF_M, wk, bk, w_wg, ws + OFF_SWG, ws + OFF_TWG,
                                        w_out, b_out, ws + OFF_SOUT, ws + OFF_TOUT, ws + OFF_SC,
                                        (unsigned short*)(ws + OFF_W7), ws + OFF_B6);
    final_mfma_kernel<<<NB * 2 * 128, 256, 0, stream>>>((const unsigned short*)(ws + OFF_W7),
                                                        xh, ws + OFF_B6, out);
}

// Round 15
// 220.186 us; speedup vs baseline: 1.1482x; 1.0954x over previous
//
#include <hip/hip_runtime.h>
#include <hip/hip_fp16.h>

#define NPIX 16384
#define CCH 256
#define INTR 128
#define REDD 32
#define NB 8
#define SLOPE 0.1f
#define BNEPS 1e-5f

typedef _Float16 f16x8 __attribute__((ext_vector_type(8)));
typedef __attribute__((ext_vector_type(16))) float f32x16;
typedef __attribute__((ext_vector_type(4))) float f32x4;

// workspace offsets (floats)
#define OFF_GX    0            // 8*256*256 = 524288
#define OFF_YM    524288       // 2048 raw row sums (written by cvtrow)
#define OFF_SC    526336       // 2048
#define OFF_QS    530432       // 1024
#define OFF_VS    531456       // 1024
#define OFF_SWG   532480       // 128
#define OFF_TWG   532608       // 128
#define OFF_SOUT  532736       // 256
#define OFF_TOUT  532992       // 256
#define OFF_M     795392       // 8*128*128 = 131072
#define OFF_W7    1450752      // ushort f16 [8*256*256] = 1 MB
#define OFF_B6    1975040      // 2048 -> ends 1977088
#define OFF_XH    1977088      // ushort f16 x [8*256*16384] = 64 MB
#define OFF_PART  18754304     // f16 partials: NB*3*nch*16384 shorts (nch=32)

__device__ __forceinline__ unsigned short h1(float f) {
    __half h = __float2half(f);
    return __half_as_ushort(h);
}

__device__ __forceinline__ uint4 cvt8h(const float4 a, const float4 c) {
    __half2 p0 = __floats2half2_rn(a.x, a.y);
    __half2 p1 = __floats2half2_rn(a.z, a.w);
    __half2 p2 = __floats2half2_rn(c.x, c.y);
    __half2 p3 = __floats2half2_rn(c.z, c.w);
    uint4 r;
    r.x = *(unsigned int*)&p0; r.y = *(unsigned int*)&p1;
    r.z = *(unsigned int*)&p2; r.w = *(unsigned int*)&p3;
    return r;
}

__device__ __forceinline__ uint4 cvt8hv(const f32x4 a, const f32x4 c) {
    __half2 p0 = __floats2half2_rn(a[0], a[1]);
    __half2 p1 = __floats2half2_rn(a[2], a[3]);
    __half2 p2 = __floats2half2_rn(c[0], c[1]);
    __half2 p3 = __floats2half2_rn(c[2], c[3]);
    uint4 r;
    r.x = *(unsigned int*)&p0; r.y = *(unsigned int*)&p1;
    r.z = *(unsigned int*)&p2; r.w = *(unsigned int*)&p3;
    return r;
}

__device__ __forceinline__ f16x8 cvt8hf(const float4 a, const float4 c) {
    uint4 u = cvt8h(a, c);
    return *(f16x8*)&u;
}

__device__ __forceinline__ void gload_lds16(const void* g, void* l) {
    __builtin_amdgcn_global_load_lds((const __attribute__((address_space(1))) void*)g,
                                     (__attribute__((address_space(3))) void*)l, 16, 0, 0);
}

// ---------- 1. x f32 -> xh f16 (once) + fused row sums; x is read-once -> nontemporal ----------
__global__ __launch_bounds__(256) void cvtrow_kernel(const float* __restrict__ x,
                                                     unsigned short* __restrict__ xh,
                                                     float* __restrict__ ymsum) {
    int row = blockIdx.x;  // b*256 + c
    const f32x4* p4 = (const f32x4*)(x + (size_t)row * NPIX);
    uint4* o4 = (uint4*)(xh + (size_t)row * NPIX);
    float s = 0.f;
    for (int i = threadIdx.x; i < NPIX / 8; i += 256) {
        f32x4 v0 = __builtin_nontemporal_load(&p4[2 * i]);
        f32x4 v1 = __builtin_nontemporal_load(&p4[2 * i + 1]);
        s += (v0[0] + v0[1]) + (v0[2] + v0[3]) + (v1[0] + v1[1]) + (v1[2] + v1[3]);
        o4[i] = cvt8hv(v0, v1);   // xh IS re-read (gram, final) -> keep cached
    }
    for (int off = 32; off > 0; off >>= 1) s += __shfl_xor(s, off);
    __shared__ float red[4];
    if ((threadIdx.x & 63) == 0) red[threadIdx.x >> 6] = s;
    __syncthreads();
    if (threadIdx.x == 0)
        ymsum[row] = red[0] + red[1] + red[2] + red[3];
}

// ---------- 2. head: SE + BN-prep + qs/vs, fused ----------
__global__ __launch_bounds__(256) void head_kernel(const float* __restrict__ ymsum,
                                                   const float* __restrict__ se_w1,
                                                   const float* __restrict__ se_w2,
                                                   const float* __restrict__ wq,
                                                   const float* __restrict__ wv,
                                                   const float* __restrict__ g_wg, const float* __restrict__ be_wg,
                                                   const float* __restrict__ rm_wg, const float* __restrict__ rv_wg,
                                                   const float* __restrict__ g_out, const float* __restrict__ be_out,
                                                   const float* __restrict__ rm_out, const float* __restrict__ rv_out,
                                                   float* __restrict__ scale,
                                                   float* __restrict__ qs, float* __restrict__ vs,
                                                   float* __restrict__ swg, float* __restrict__ twg,
                                                   float* __restrict__ sout, float* __restrict__ tout) {
    int b = blockIdx.x, t = threadIdx.x;
    __shared__ float ys[CCH], y1s[REDD], rs[CCH];
    float ymr = ymsum[b * CCH + t];
    ys[t] = ymr * (1.f / 16384.f);
    if (b == 0) {
        if (t < INTR) {
            float s = g_wg[t] / sqrtf(rv_wg[t] + BNEPS);
            swg[t] = s;
            twg[t] = be_wg[t] - rm_wg[t] * s;
        }
        float s = g_out[t] / sqrtf(rv_out[t] + BNEPS);
        sout[t] = s;
        tout[t] = be_out[t] - rm_out[t] * s;
    }
    __syncthreads();
    if (t < REDD) {
        float a = 0.f;
        #pragma unroll 4
        for (int c = 0; c < CCH; ++c) a += se_w1[t * CCH + c] * ys[c];
        y1s[t] = a > 0.f ? a : SLOPE * a;
    }
    __syncthreads();
    float a = 0.f;
    #pragma unroll
    for (int r = 0; r < REDD; ++r) a += se_w2[t * REDD + r] * y1s[r];
    float sg = 1.f / (1.f + expf(-a));
    scale[b * CCH + t] = sg;
    rs[t] = sg * ymr;
    __syncthreads();
    const float* w = (t < INTR) ? (wq + t * CCH) : (wv + (t - INTR) * CCH);
    float a2 = 0.f;
    #pragma unroll 4
    for (int c = 0; c < CCH; ++c) a2 += w[c] * rs[c];
    if (t < INTR) qs[b * INTR + t] = a2;
    else          vs[b * INTR + (t - INTR)] = a2;
}

// ---------- 5a. Gram split-K: R10 version (xh via global_load_lds, f16 partials) ----------
__global__ __launch_bounds__(256) void gram_partial_kernel(const unsigned short* __restrict__ xh,
                                                           unsigned short* __restrict__ partials,
                                                           int nch) {
    __shared__ __align__(16) unsigned short Ah[128 * 64];
    __shared__ __align__(16) unsigned short Bh[128 * 64];
    int bid = blockIdx.x;
    int chunk = bid % nch;
    int t2 = bid / nch;
    int tile = t2 % 3;
    int b = t2 / 3;
    int rowbase = (tile == 1) ? 128 : 0;
    int colbase = (tile == 0) ? 0 : 128;
    bool diag = (tile < 2);
    const unsigned short* xb = xh + (size_t)b * CCH * NPIX;
    int kpb = NPIX / nch;
    int n0 = chunk * kpb;
    int nsteps = kpb >> 6;
    int tid = threadIdx.x;
    int l = tid & 63, w = tid >> 6;
    int wrow = (w >> 1) * 64, wcol = (w & 1) * 64;
    int sr = l >> 3, ssg = l & 7;

    f32x16 acc[2][2];
    #pragma unroll
    for (int i = 0; i < 2; ++i)
        #pragma unroll
        for (int j = 0; j < 2; ++j)
            #pragma unroll
            for (int r = 0; r < 16; ++r) acc[i][j][r] = 0.f;

    for (int step = 0; step < nsteps; ++step) {
        int k0 = n0 + step * 64;
        __syncthreads();
        #pragma unroll
        for (int e = 0; e < 4; ++e) {
            int rbase = e * 32 + w * 8;
            int r = rbase + sr;
            int seg = ssg ^ (r & 7);
            gload_lds16(&xb[(size_t)(rowbase + r) * NPIX + k0 + seg * 8], &Ah[rbase * 64]);
            if (!diag)
                gload_lds16(&xb[(size_t)(colbase + r) * NPIX + k0 + seg * 8], &Bh[rbase * 64]);
        }
        __syncthreads();
        const unsigned short* BP = diag ? Ah : Bh;
        #pragma unroll
        for (int kk = 0; kk < 4; ++kk) {
            int useg = kk * 2 + (l >> 5);
            f16x8 af[2], bf[2];
            #pragma unroll
            for (int at = 0; at < 2; ++at) {
                int r = wrow + at * 32 + (l & 31);
                af[at] = *(const f16x8*)&Ah[r * 64 + ((useg ^ (r & 7)) << 3)];
            }
            #pragma unroll
            for (int bt = 0; bt < 2; ++bt) {
                int c = wcol + bt * 32 + (l & 31);
                bf[bt] = *(const f16x8*)&BP[c * 64 + ((useg ^ (c & 7)) << 3)];
            }
            #pragma unroll
            for (int at = 0; at < 2; ++at)
                #pragma unroll
                for (int bt = 0; bt < 2; ++bt)
                    acc[at][bt] = __builtin_amdgcn_mfma_f32_32x32x16_f16(af[at], bf[bt], acc[at][bt], 0, 0, 0);
        }
    }
    unsigned short* P = partials + (size_t)bid * (128 * 128);
    #pragma unroll
    for (int at = 0; at < 2; ++at)
        #pragma unroll
        for (int bt = 0; bt < 2; ++bt)
            #pragma unroll
            for (int r = 0; r < 16; ++r) {
                int lr = wrow + at * 32 + (r & 3) + ((r >> 2) << 3) + ((l >> 5) << 2);
                int lc = wcol + bt * 32 + (l & 31);
                P[lr * 128 + lc] = h1(acc[at][bt][r]);
            }
}

// ---------- 5b. reduce f16 partials -> G (f32) ----------
__global__ __launch_bounds__(256) void gram_reduce_kernel(const unsigned short* __restrict__ partials,
                                                          float* __restrict__ Gx,
                                                          int nch) {
    int bid = blockIdx.x;
    int part = bid & 15;
    int tileIdx = bid >> 4;
    int tile = tileIdx % 3;
    int b = tileIdx / 3;
    int rowbase = (tile == 1) ? 128 : 0;
    int colbase = (tile == 0) ? 0 : 128;
    int locIdx = part * 1024 + threadIdx.x * 4;
    const unsigned short* P = partials + (size_t)tileIdx * nch * (128 * 128) + locIdx;
    float4 s = make_float4(0.f, 0.f, 0.f, 0.f);
    for (int ch = 0; ch < nch; ++ch) {
        ushort4 v = *(const ushort4*)(P + (size_t)ch * (128 * 128));
        s.x += __half2float(__ushort_as_half(v.x));
        s.y += __half2float(__ushort_as_half(v.y));
        s.z += __half2float(__ushort_as_half(v.z));
        s.w += __half2float(__ushort_as_half(v.w));
    }
    int lr = locIdx >> 7, lc = locIdx & 127;
    float* G = Gx + (size_t)b * CCH * CCH;
    *(float4*)&G[(rowbase + lr) * CCH + colbase + lc] = s;
    if (tile == 2) {
        G[(colbase + lc + 0) * CCH + rowbase + lr] = s.x;
        G[(colbase + lc + 1) * CCH + rowbase + lr] = s.y;
        G[(colbase + lc + 2) * CCH + rowbase + lr] = s.z;
        G[(colbase + lc + 3) * CCH + rowbase + lr] = s.w;
    }
}

// ---------- 6+7 fused: T1 row -> S row -> softmax -> M[b,j,i] ----------
__global__ __launch_bounds__(256) void ts_kernel(const float* __restrict__ wq,
                                                 const float* __restrict__ scale,
                                                 const float* __restrict__ Gx,
                                                 const float* __restrict__ wv,
                                                 const float* __restrict__ bq,
                                                 const float* __restrict__ bv,
                                                 const float* __restrict__ qs,
                                                 const float* __restrict__ vs,
                                                 float* __restrict__ M) {
    int bid = blockIdx.x;
    int i = bid & 127, b = bid >> 7;
    int t = threadIdx.x;
    __shared__ float sw[CCH];
    __shared__ float t1s[CCH];
    __shared__ float part[256];
    __shared__ float redm[2], reds[2];
    sw[t] = wq[i * CCH + t] * scale[b * CCH + t];
    __syncthreads();
    const float* G = Gx + (size_t)b * CCH * CCH;
    float acc = 0.f;
    #pragma unroll 4
    for (int c = 0; c < CCH; ++c) acc += sw[c] * G[c * CCH + t];
    t1s[t] = acc * scale[b * CCH + t];
    __syncthreads();
    int j = t & 127, h = t >> 7;
    const float* wvr = wv + j * CCH + h * 128;
    const float* tp = t1s + h * 128;
    float p = 0.f;
    #pragma unroll 4
    for (int c = 0; c < 128; ++c) p += tp[c] * wvr[c];
    part[t] = p;
    __syncthreads();
    float acc2 = 0.f;
    if (t < 128)
        acc2 = part[t] + part[t + 128]
             + bq[i] * vs[b * INTR + j] + bv[j] * qs[b * INTR + i] + 16384.f * bq[i] * bv[j];
    float m = acc2;
    for (int off = 32; off > 0; off >>= 1) m = fmaxf(m, __shfl_xor(m, off));
    if (t == 0) redm[0] = m;
    if (t == 64) redm[1] = m;
    __syncthreads();
    m = fmaxf(redm[0], redm[1]);
    float e = expf(acc2 - m);
    float s = e;
    for (int off = 32; off > 0; off >>= 1) s += __shfl_xor(s, off);
    if (t == 0) reds[0] = s;
    if (t == 64) reds[1] = s;
    __syncthreads();
    s = reds[0] + reds[1];
    if (t < 128)
        M[(size_t)b * INTR * INTR + j * INTR + i] = e / s;   // transposed store
}

// ---------- 8-11 fused tail: M -> Wav -> W2 -> W7h (+bias chain -> b6), one block per batch ----------
__global__ __launch_bounds__(256) void tail_kernel(const float* __restrict__ M,
                                                   const float* __restrict__ wk,
                                                   const float* __restrict__ bk,
                                                   const float* __restrict__ wwg,
                                                   const float* __restrict__ swg,
                                                   const float* __restrict__ twg,
                                                   const float* __restrict__ wout,
                                                   const float* __restrict__ bout,
                                                   const float* __restrict__ sout,
                                                   const float* __restrict__ tout,
                                                   const float* __restrict__ scale,
                                                   unsigned short* __restrict__ W7h,
                                                   float* __restrict__ b6) {
    __shared__ __align__(16) unsigned short Bt[256 * 128];
    __shared__ __align__(16) unsigned short Ot[256 * 128];
    __shared__ float bavS[INTR], b2S[INTR], scS[CCH], soS[CCH], swgS[INTR];
    int b = blockIdx.x, tid = threadIdx.x;
    int l = tid & 63, w = tid >> 6;
    const float* Mb = M + (size_t)b * INTR * INTR;

    scS[tid] = scale[b * CCH + tid];
    soS[tid] = sout[tid];
    if (tid < INTR) swgS[tid] = swg[tid];

    {
        int mn = tid & 63;
        int mk0 = tid >> 6;
        #pragma unroll
        for (int e = 0; e < 8; ++e) {
            int j0 = (mk0 + 4 * e) * 4;
            int c0 = mn * 4;
            float4 q0 = *(const float4*)&wk[(size_t)(j0 + 0) * CCH + c0];
            float4 q1 = *(const float4*)&wk[(size_t)(j0 + 1) * CCH + c0];
            float4 q2 = *(const float4*)&wk[(size_t)(j0 + 2) * CCH + c0];
            float4 q3 = *(const float4*)&wk[(size_t)(j0 + 3) * CCH + c0];
            int unit = j0 >> 3, sub = (j0 >> 2) & 1;
            int key = (c0 >> 2) & 7;
            #pragma unroll
            for (int jj = 0; jj < 4; ++jj) {
                float e0 = jj == 0 ? q0.x : jj == 1 ? q0.y : jj == 2 ? q0.z : q0.w;
                float e1 = jj == 0 ? q1.x : jj == 1 ? q1.y : jj == 2 ? q1.z : q1.w;
                float e2 = jj == 0 ? q2.x : jj == 1 ? q2.y : jj == 2 ? q2.z : q2.w;
                float e3 = jj == 0 ? q3.x : jj == 1 ? q3.y : jj == 2 ? q3.z : q3.w;
                ushort4 cv = make_ushort4(h1(e0), h1(e1), h1(e2), h1(e3));
                *(ushort4*)&Bt[(c0 + jj) * 128 + ((unit ^ key) << 3) + sub * 4] = cv;
            }
        }
    }
    if (tid < INTR) {
        float a = 0.f;
        #pragma unroll 4
        for (int j = 0; j < INTR; ++j) a += Mb[tid * INTR + j] * bk[j];
        bavS[tid] = a;
    }
    __syncthreads();

    {
        f32x16 acc[4][2];
        #pragma unroll
        for (int at = 0; at < 4; ++at)
            #pragma unroll
            for (int bt = 0; bt < 2; ++bt)
                #pragma unroll
                for (int r = 0; r < 16; ++r) acc[at][bt][r] = 0.f;
        #pragma unroll
        for (int kk = 0; kk < 8; ++kk) {
            int useg = kk * 2 + (l >> 5);
            f16x8 bf[2];
            #pragma unroll
            for (int bt = 0; bt < 2; ++bt) {
                int c = w * 64 + bt * 32 + (l & 31);
                bf[bt] = *(const f16x8*)&Bt[c * 128 + ((useg ^ ((c >> 2) & 7)) << 3)];
            }
            #pragma unroll
            for (int at = 0; at < 4; ++at) {
                int i = at * 32 + (l & 31);
                float4 a0 = *(const float4*)&Mb[(size_t)i * INTR + useg * 8];
                float4 a1 = *(const float4*)&Mb[(size_t)i * INTR + useg * 8 + 4];
                f16x8 af = cvt8hf(a0, a1);
                #pragma unroll
                for (int bt = 0; bt < 2; ++bt)
                    acc[at][bt] = __builtin_amdgcn_mfma_f32_32x32x16_f16(af, bf[bt], acc[at][bt], 0, 0, 0);
            }
        }
        if (tid < INTR) {
            float a = 0.f;
            #pragma unroll 4
            for (int i = 0; i < INTR; ++i) a += wwg[tid * INTR + i] * bavS[i];
            b2S[tid] = swgS[tid] * a + twg[tid];
        }
        __syncthreads();
        #pragma unroll
        for (int at = 0; at < 4; ++at)
            #pragma unroll
            for (int bt = 0; bt < 2; ++bt)
                #pragma unroll
                for (int r = 0; r < 16; ++r) {
                    int i = at * 32 + (r & 3) + ((r >> 2) << 3) + ((l >> 5) << 2);
                    int c = w * 64 + bt * 32 + (l & 31);
                    Ot[c * 128 + (((i >> 3) ^ ((c >> 2) & 7)) << 3) + (i & 7)] = h1(acc[at][bt][r]);
                }
    }
    __syncthreads();

    {
        f32x16 acc[4][2];
        #pragma unroll
        for (int at = 0; at < 4; ++at)
            #pragma unroll
            for (int bt = 0; bt < 2; ++bt)
                #pragma unroll
                for (int r = 0; r < 16; ++r) acc[at][bt][r] = 0.f;
        #pragma unroll
        for (int kk = 0; kk < 8; ++kk) {
            int useg = kk * 2 + (l >> 5);
            f16x8 bf[2];
            #pragma unroll
            for (int bt = 0; bt < 2; ++bt) {
                int c = w * 64 + bt * 32 + (l & 31);
                bf[bt] = *(const f16x8*)&Ot[c * 128 + ((useg ^ ((c >> 2) & 7)) << 3)];
            }
            #pragma unroll
            for (int at = 0; at < 4; ++at) {
                int o = at * 32 + (l & 31);
                float4 a0 = *(const float4*)&wwg[(size_t)o * INTR + useg * 8];
                float4 a1 = *(const float4*)&wwg[(size_t)o * INTR + useg * 8 + 4];
                f16x8 af = cvt8hf(a0, a1);
                #pragma unroll
                for (int bt = 0; bt < 2; ++bt)
                    acc[at][bt] = __builtin_amdgcn_mfma_f32_32x32x16_f16(af, bf[bt], acc[at][bt], 0, 0, 0);
            }
        }
        {
            float a = 0.f;
            #pragma unroll 4
            for (int o = 0; o < INTR; ++o) a += wout[tid * INTR + o] * b2S[o];
            float b5 = a + bout[tid];
            b6[b * CCH + tid] = soS[tid] * b5 + tout[tid];
        }
        __syncthreads();
        #pragma unroll
        for (int at = 0; at < 4; ++at)
            #pragma unroll
            for (int bt = 0; bt < 2; ++bt)
                #pragma unroll
                for (int r = 0; r < 16; ++r) {
                    int o = at * 32 + (r & 3) + ((r >> 2) << 3) + ((l >> 5) << 2);
                    int c = w * 64 + bt * 32 + (l & 31);
                    Bt[c * 128 + (((o >> 3) ^ ((c >> 2) & 7)) << 3) + (o & 7)] = h1(swgS[o] * acc[at][bt][r]);
                }
    }
    __syncthreads();

    unsigned short* Wb = W7h + (size_t)b * CCH * CCH;
    #pragma unroll
    for (int p = 0; p < 2; ++p) {
        f32x16 acc[4][2];
        #pragma unroll
        for (int at = 0; at < 4; ++at)
            #pragma unroll
            for (int bt = 0; bt < 2; ++bt)
                #pragma unroll
                for (int r = 0; r < 16; ++r) acc[at][bt][r] = 0.f;
        #pragma unroll
        for (int kk = 0; kk < 8; ++kk) {
            int useg = kk * 2 + (l >> 5);
            f16x8 bf[2];
            #pragma unroll
            for (int bt = 0; bt < 2; ++bt) {
                int cp = w * 64 + bt * 32 + (l & 31);
                bf[bt] = *(const f16x8*)&Bt[cp * 128 + ((useg ^ ((cp >> 2) & 7)) << 3)];
            }
            #pragma unroll
            for (int at = 0; at < 4; ++at) {
                int cc = p * 128 + at * 32 + (l & 31);
                float4 a0 = *(const float4*)&wout[(size_t)cc * INTR + useg * 8];
                float4 a1 = *(const float4*)&wout[(size_t)cc * INTR + useg * 8 + 4];
                f16x8 af = cvt8hf(a0, a1);
                #pragma unroll
                for (int bt = 0; bt < 2; ++bt)
                    acc[at][bt] = __builtin_amdgcn_mfma_f32_32x32x16_f16(af, bf[bt], acc[at][bt], 0, 0, 0);
            }
        }
        #pragma unroll
        for (int at = 0; at < 4; ++at)
            #pragma unroll
            for (int bt = 0; bt < 2; ++bt)
                #pragma unroll
                for (int r = 0; r < 16; ++r) {
                    int c = p * 128 + at * 32 + (r & 3) + ((r >> 2) << 3) + ((l >> 5) << 2);
                    int cp = w * 64 + bt * 32 + (l & 31);
                    float w6 = soS[c] * acc[at][bt][r] + ((c == cp) ? 1.f : 0.f);
                    Wb[c * CCH + cp] = h1(w6 * scS[cp]);
                }
    }
}

// ---------- 12. out = leaky(W7 @ xh + b6), R10 version + nontemporal out stores ----------
__global__ __launch_bounds__(256, 4) void final_mfma_kernel(const unsigned short* __restrict__ W7h,
                                                            const unsigned short* __restrict__ xh,
                                                            const float* __restrict__ b6,
                                                            float* __restrict__ out) {
    __shared__ __align__(16) unsigned short Ws[128 * 64];
    __shared__ __align__(16) unsigned short Xs[128 * 64];
    int bid0 = blockIdx.x;
    int bid = (bid0 & 7) * 256 + (bid0 >> 3);   // bijective XCD swizzle (2048 % 8 == 0)
    int ct = bid & 1;
    int nt = (bid >> 1) & 127;
    int b = bid >> 8;
    int cbase = ct * 128, n0 = nt * 128;
    const unsigned short* xb = xh + (size_t)b * CCH * NPIX;
    const unsigned short* Wb = W7h + (size_t)b * CCH * CCH;
    int tid = threadIdx.x;
    int l = tid & 63, w = tid >> 6;
    int wrow = (w >> 1) * 64, wcol = (w & 1) * 64;
    int mn = tid & 31, mk0 = tid >> 5;
    int sr = l >> 3, ssg = l & 7;

    f32x16 acc[2][2];
    #pragma unroll
    for (int i = 0; i < 2; ++i)
        #pragma unroll
        for (int j = 0; j < 2; ++j)
            #pragma unroll
            for (int r = 0; r < 16; ++r) acc[i][j][r] = 0.f;

    for (int step = 0; step < 4; ++step) {
        int k0 = step * 64;
        __syncthreads();
        #pragma unroll
        for (int e = 0; e < 4; ++e) {
            int rbase = e * 32 + w * 8;
            int r = rbase + sr;
            int seg = ssg ^ (r & 7);
            gload_lds16(&Wb[(size_t)(cbase + r) * CCH + k0 + seg * 8], &Ws[rbase * 64]);
        }
        #pragma unroll
        for (int mi = 0; mi < 2; ++mi) {
            int mk = mk0 + mi * 8;
            const unsigned short* sp = &xb[(size_t)(k0 + mk * 4) * NPIX + n0 + mn * 4];
            ushort4 q0 = *(const ushort4*)sp;
            ushort4 q1 = *(const ushort4*)(sp + NPIX);
            ushort4 q2 = *(const ushort4*)(sp + 2 * NPIX);
            ushort4 q3 = *(const ushort4*)(sp + 3 * NPIX);
            int klo = mk * 4;
            int unit = klo >> 3, sub = (klo & 7) >> 2;
            #pragma unroll
            for (int j = 0; j < 4; ++j) {
                unsigned short e0 = j == 0 ? q0.x : j == 1 ? q0.y : j == 2 ? q0.z : q0.w;
                unsigned short e1 = j == 0 ? q1.x : j == 1 ? q1.y : j == 2 ? q1.z : q1.w;
                unsigned short e2 = j == 0 ? q2.x : j == 1 ? q2.y : j == 2 ? q2.z : q2.w;
                unsigned short e3 = j == 0 ? q3.x : j == 1 ? q3.y : j == 2 ? q3.z : q3.w;
                int nl = mn * 4 + j;
                ushort4 cv = make_ushort4(e0, e1, e2, e3);
                int idx = nl * 64 + ((unit ^ ((nl >> 2) & 7)) << 3) + sub * 4;
                *(ushort4*)&Xs[idx] = cv;
            }
        }
        __syncthreads();
        #pragma unroll
        for (int kk = 0; kk < 4; ++kk) {
            int useg = kk * 2 + (l >> 5);
            f16x8 af[2], bfr[2];
            #pragma unroll
            for (int at = 0; at < 2; ++at) {
                int c = wrow + at * 32 + (l & 31);
                af[at] = *(const f16x8*)&Ws[c * 64 + ((useg ^ (c & 7)) << 3)];
            }
            #pragma unroll
            for (int bt = 0; bt < 2; ++bt) {
                int n = wcol + bt * 32 + (l & 31);
                bfr[bt] = *(const f16x8*)&Xs[n * 64 + ((useg ^ ((n >> 2) & 7)) << 3)];
            }
            #pragma unroll
            for (int at = 0; at < 2; ++at)
                #pragma unroll
                for (int bt = 0; bt < 2; ++bt)
                    acc[at][bt] = __builtin_amdgcn_mfma_f32_32x32x16_f16(af[at], bfr[bt], acc[at][bt], 0, 0, 0);
        }
    }
    #pragma unroll
    for (int at = 0; at < 2; ++at)
        #pragma unroll
        for (int bt = 0; bt < 2; ++bt)
            #pragma unroll
            for (int r = 0; r < 16; ++r) {
                int c = cbase + wrow + at * 32 + (r & 3) + ((r >> 2) << 3) + ((l >> 5) << 2);
                int n = n0 + wcol + bt * 32 + (l & 31);
                float v = acc[at][bt][r] + b6[b * CCH + c];
                v = v > 0.f ? v : SLOPE * v;
                __builtin_nontemporal_store(v, &out[(size_t)b * CCH * NPIX + (size_t)c * NPIX + n]);
            }
}

extern "C" void kernel_launch(void* const* d_in, const int* in_sizes, int n_in,
                              void* d_out, int out_size, void* d_ws, size_t ws_size,
                              hipStream_t stream) {
    (void)in_sizes; (void)n_in; (void)out_size;
    const float* x      = (const float*)d_in[0];
    const float* se_w1  = (const float*)d_in[1];
    const float* se_w2  = (const float*)d_in[2];
    const float* wq     = (const float*)d_in[3];
    const float* bq     = (const float*)d_in[4];
    const float* wk     = (const float*)d_in[5];
    const float* bk     = (const float*)d_in[6];
    const float* wv     = (const float*)d_in[7];
    const float* bv     = (const float*)d_in[8];
    const float* w_wg   = (const float*)d_in[9];
    const float* w_out  = (const float*)d_in[14];
    const float* b_out  = (const float*)d_in[15];
    float* out = (float*)d_out;
    float* ws = (float*)d_ws;
    unsigned short* xh = (unsigned short*)(ws + OFF_XH);

    size_t avail = ws_size / sizeof(float);
    int nch = 32;
    while (nch > 1 && (size_t)OFF_PART + (size_t)NB * 3 * nch * 8192 > avail) nch >>= 1;

    cvtrow_kernel<<<NB * CCH, 256, 0, stream>>>(x, xh, ws + OFF_YM);
    gram_partial_kernel<<<NB * 3 * nch, 256, 0, stream>>>(xh, (unsigned short*)(ws + OFF_PART), nch);
    gram_reduce_kernel<<<NB * 3 * 16, 256, 0, stream>>>((const unsigned short*)(ws + OFF_PART),
                                                        ws + OFF_GX, nch);
    head_kernel<<<NB, 256, 0, stream>>>(ws + OFF_YM, se_w1, se_w2, wq, wv,
                                        (const float*)d_in[10], (const float*)d_in[11],
                                        (const float*)d_in[12], (const float*)d_in[13],
                                        (const float*)d_in[16], (const float*)d_in[17],
                                        (const float*)d_in[18], (const float*)d_in[19],
                                        ws + OFF_SC, ws + OFF_QS, ws + OFF_VS,
                                        ws + OFF_SWG, ws + OFF_TWG, ws + OFF_SOUT, ws + OFF_TOUT);
    ts_kernel<<<NB * INTR, 256, 0, stream>>>(wq, ws + OFF_SC, ws + OFF_GX, wv, bq, bv,
                                             ws + OFF_QS, ws + OFF_VS, ws + OFF_M);
    tail_kernel<<<NB, 256, 0, stream>>>(ws + OFF_M, wk, bk, w_wg, ws + OFF_SWG, ws + OFF_TWG,
                                        w_out, b_out, ws + OFF_SOUT, ws + OFF_TOUT, ws + OFF_SC,
                                        (unsigned short*)(ws + OFF_W7), ws + OFF_B6);
    final_mfma_kernel<<<NB * 2 * 128, 256, 0, stream>>>((const unsigned short*)(ws + OFF_W7),
                                                        xh, ws + OFF_B6, out);
}